// Round 1
// baseline (1386.830 us; speedup 1.0000x reference)
//
#include <hip/hip_runtime.h>
#include <cstddef>

#define NS 512
#define NL 5
#define NT 20
#define NE 768
#define NH 64
#define NG 256   // 4*H
#define BK 16

__device__ __forceinline__ float sigf(float x) { return 1.0f / (1.0f + expf(-x)); }
// wave-uniform broadcast of lane k's value via VALU pipe (no LDS traffic)
__device__ __forceinline__ float bcast(float v, int k) {
    return __int_as_float(__builtin_amdgcn_readlane(__float_as_int(v), k));
}

// ---------------------------------------------------------------------------
// Kernel 1 (unchanged this round): u[s][t][l][g] = x[s][l][t][:] . Uall[s][:][g]
// ---------------------------------------------------------------------------
__global__ __launch_bounds__(640) void k_gemm_u(
    const float* __restrict__ x, const float* __restrict__ U,
    const float* __restrict__ bU, float* __restrict__ u)
{
    __shared__ float xs[100 * BK];    // 6400 B
    __shared__ float Us[BK * 128];    // 8192 B
    const int bid = blockIdx.x;
    const int s = bid >> 1, half = bid & 1;
    const int tid = threadIdx.x;
    const float* xg = x + (size_t)s * (NL * NT * NE);
    const float* Ug = U + (size_t)s * (NE * NG) + half * 128;
    const int wave = tid >> 6, lane = tid & 63;
    const int r0 = wave * 10;
    float acc0[10], acc1[10];
    #pragma unroll
    for (int i = 0; i < 10; ++i) { acc0[i] = 0.0f; acc1[i] = 0.0f; }

    for (int e0 = 0; e0 < NE; e0 += BK) {
        if (tid < 400) {
            int row = tid >> 2;
            int kq = (tid & 3) * 4;
            *(float4*)&xs[row * BK + kq] =
                *(const float4*)(xg + (size_t)row * NE + e0 + kq);
        }
        if (tid < 512) {
            int k = tid >> 5, c4 = (tid & 31) * 4;
            *(float4*)&Us[k * 128 + c4] =
                *(const float4*)(Ug + (size_t)(e0 + k) * NG + c4);
        }
        __syncthreads();
        #pragma unroll
        for (int k4 = 0; k4 < BK; k4 += 4) {
            float ua0 = Us[(k4 + 0) * 128 + lane];
            float ua1 = Us[(k4 + 1) * 128 + lane];
            float ua2 = Us[(k4 + 2) * 128 + lane];
            float ua3 = Us[(k4 + 3) * 128 + lane];
            float ub0 = Us[(k4 + 0) * 128 + 64 + lane];
            float ub1 = Us[(k4 + 1) * 128 + 64 + lane];
            float ub2 = Us[(k4 + 2) * 128 + 64 + lane];
            float ub3 = Us[(k4 + 3) * 128 + 64 + lane];
            #pragma unroll
            for (int rr = 0; rr < 10; ++rr) {
                float4 xv = *(const float4*)&xs[(r0 + rr) * BK + k4];
                acc0[rr] += xv.x * ua0 + xv.y * ua1 + xv.z * ua2 + xv.w * ua3;
                acc1[rr] += xv.x * ub0 + xv.y * ub1 + xv.z * ub2 + xv.w * ub3;
            }
        }
        __syncthreads();
    }
    const float bv0 = bU[(size_t)s * NG + half * 128 + lane];
    const float bv1 = bU[(size_t)s * NG + half * 128 + 64 + lane];
    #pragma unroll
    for (int rr = 0; rr < 10; ++rr) {
        int r = r0 + rr;
        int l = r / 20, t = r % 20;
        size_t base = (((size_t)s * NT + t) * NL + l) * NG + half * 128 + lane;
        u[base]      = acc0[rr] + bv0;
        u[base + 64] = acc1[rr] + bv1;
    }
}

// ---------------------------------------------------------------------------
// Kernel 2 v3: latency-bound recurrence restructured.
//  - Wall columns live in per-thread VGPRs (64 regs, tid<256): zero LDS
//    traffic for the gate matmul weights.
//  - h[l][k] / c[l][k] broadcasts come from v_readlane of the owning wave's
//    registers (VALU pipe) instead of ds_read broadcasts.
//  - c state is register-only; CS LDS region gone. W1 aliases dead Wd space.
//  - LDS 119 KB -> 67.3 KB  => 2 blocks/CU, all 512 blocks resident in ONE
//    round, 10 waves/CU (was 5).  __launch_bounds__(320,3) caps VGPR at 170
//    so 3-wave SIMDs fit (est. usage ~120, no spill).
// ---------------------------------------------------------------------------
#define WD    0        // 4096 fl; aliased by W1 after the recurrence
#define W1OFF 0
#define W2OFF 4096     // 4096 fl
#define FULLO 8192     // 6400 fl: o-gates [l][t][h]
#define HS    14592    // 320
#define TQ    14912    // 320: q, then hd
#define CA    15232    // 320: text_vec
#define GATES 15552    // 1280
#define TS    16832    // 100
#define SC    16932    // 100
#define B0    17032    // 64: b1
#define B1    17096    // 64: b2
#define BVV   17160    // 64: V
#define BV1   17224    // 1
#define SMTOT 17228    // 68912 B

__global__ __launch_bounds__(320, 3) void k_stock(
    const float* __restrict__ u, const float* __restrict__ ti,
    const float* __restrict__ Wall, const float* __restrict__ bWall,
    const float* __restrict__ Wd, const float* __restrict__ bWd,
    const float* __restrict__ W1, const float* __restrict__ b1,
    const float* __restrict__ W2, const float* __restrict__ b2,
    const float* __restrict__ V, const float* __restrict__ bV,
    const float* __restrict__ Wih, const float* __restrict__ bih,
    const float* __restrict__ bhh, const float* __restrict__ lin_w,
    const float* __restrict__ lin_b, float* __restrict__ out)
{
    __shared__ float sm[SMTOT];
    const int s = blockIdx.x;
    const int tid = threadIdx.x;
    const int lq = tid >> 6, hh = tid & 63;   // (l, h) item for 320-wide ops
    const int lane = hh;
    const float* ug = u + (size_t)s * NT * NL * NG;

    // ---- init: Wd + W2 + biases to LDS; Wall column + bWd to registers ----
    for (int i = tid; i < 1024; i += 320)
        *(float4*)&sm[WD + i * 4] = *(const float4*)(Wd + (size_t)s * 4096 + i * 4);
    for (int i = tid; i < 1024; i += 320)
        *(float4*)&sm[W2OFF + i * 4] = *(const float4*)(W2 + (size_t)s * 4096 + i * 4);
    if (tid < NH) {
        sm[B0 + tid]  = b1[(size_t)s * NH + tid];
        sm[B1 + tid]  = b2[(size_t)s * NH + tid];
        sm[BVV + tid] = V[(size_t)s * NH + tid];
    }
    if (tid == 0) sm[BV1] = bV[s];
    if (tid < NL * NT) sm[TS + tid] = ti[(size_t)s * NL * NT + tid];
    sm[HS + tid] = 0.0f;
    const float bwd_r = bWd[(size_t)s * NH + hh];
    float c_reg = 0.0f;                 // c[lq][hh], register-resident state
    float wall_r[NH];                   // Wall[:, tid] column (tid<256)
    float bwall_r = 0.0f, uc[NL];
    if (tid < NG) {
        bwall_r = bWall[(size_t)s * NG + tid];
        const float* wp = Wall + (size_t)s * (NH * NG) + tid;
        #pragma unroll
        for (int k = 0; k < NH; ++k) wall_r[k] = wp[(size_t)k * NG];
        #pragma unroll
        for (int l = 0; l < NL; ++l) uc[l] = ug[(size_t)l * NG + tid];
    }
    __syncthreads();

    // ---- TimeLSTM over T steps (gate order f,i,o,c_tmp; ALL sigmoid) ----
    for (int t = 0; t < NT; ++t) {
        float un[NL];
        if (tid < NG) {
            if (t + 1 < NT) {
                #pragma unroll
                for (int l = 0; l < NL; ++l)
                    un[l] = ug[(size_t)((t + 1) * NL + l) * NG + tid];
            } else {
                #pragma unroll
                for (int l = 0; l < NL; ++l) un[l] = 0.0f;
            }
            // h[l][lane] into this wave's own lanes, then readlane-broadcast
            float hreg[NL];
            #pragma unroll
            for (int l = 0; l < NL; ++l) hreg[l] = sm[HS + l * NH + lane];
            float gv[NL];
            #pragma unroll
            for (int l = 0; l < NL; ++l) gv[l] = bwall_r + uc[l];
            #pragma unroll
            for (int k = 0; k < NH; ++k) {
                float w = wall_r[k];
                #pragma unroll
                for (int l = 0; l < NL; ++l)
                    gv[l] += bcast(hreg[l], k) * w;
            }
            #pragma unroll
            for (int l = 0; l < NL; ++l)
                sm[GATES + l * NG + tid] = sigf(gv[l]);
        }
        // c_s1 = tanh(c@Wd + bWd); c broadcast via readlane (wave lq == l)
        float ssum = bwd_r;
        #pragma unroll
        for (int k = 0; k < NH; ++k)
            ssum += bcast(c_reg, k) * sm[WD + k * NH + hh];
        float cs1 = tanhf(ssum);
        float ca = c_reg - cs1 + cs1 * sm[TS + lq * NT + t];
        __syncthreads();
        {
            float f  = sm[GATES + lq * NG + hh];
            float ii = sm[GATES + lq * NG + 64 + hh];
            float oo = sm[GATES + lq * NG + 128 + hh];
            float ct = sm[GATES + lq * NG + 192 + hh];
            float cn = f * ca + ii * ct;
            c_reg = cn;
            sm[HS + tid] = oo * tanhf(cn);
            sm[FULLO + (lq * NT + t) * NH + hh] = oo;
        }
        __syncthreads();
        if (tid < NG) {
            #pragma unroll
            for (int l = 0; l < NL; ++l) uc[l] = un[l];
        }
    }

    // ---- W1 overwrites dead Wd LDS ----
    for (int i = tid; i < 1024; i += 320)
        *(float4*)&sm[W1OFF + i * 4] = *(const float4*)(W1 + (size_t)s * 4096 + i * 4);
    __syncthreads();

    // q = h_fin @ W1 + b1   (320 items)
    {
        float qv = sm[B0 + hh];
        for (int k4 = 0; k4 < NH; k4 += 4) {
            float4 hv = *(const float4*)&sm[HS + lq * NH + k4];
            qv += hv.x * sm[W1OFF + (k4 + 0) * NH + hh]
                + hv.y * sm[W1OFF + (k4 + 1) * NH + hh]
                + hv.z * sm[W1OFF + (k4 + 2) * NH + hh]
                + hv.w * sm[W1OFF + (k4 + 3) * NH + hh];
        }
        sm[TQ + tid] = qv;
    }
    __syncthreads();

    // scores: one wave per (l,t) item; 100 items over 5 waves
    for (int lt = lq; lt < NL * NT; lt += 5) {
        int l = lt / NT;
        float v = sm[TQ + l * NH + lane] + sm[B1 + lane];
        for (int k4 = 0; k4 < NH; k4 += 4) {
            float4 fv = *(const float4*)&sm[FULLO + lt * NH + k4];
            v += fv.x * sm[W2OFF + (k4 + 0) * NH + lane]
               + fv.y * sm[W2OFF + (k4 + 1) * NH + lane]
               + fv.z * sm[W2OFF + (k4 + 2) * NH + lane]
               + fv.w * sm[W2OFF + (k4 + 3) * NH + lane];
        }
        v = tanhf(v) * sm[BVV + lane];
        #pragma unroll
        for (int m = 32; m > 0; m >>= 1) v += __shfl_xor(v, m, 64);
        if (lane == 0) sm[SC + lt] = v + sm[BV1];
    }
    __syncthreads();

    // softmax over t per l
    if (tid < NL) {
        float mx = -1e30f;
        for (int t = 0; t < NT; ++t) mx = fmaxf(mx, sm[SC + tid * NT + t]);
        float sum = 0.0f;
        for (int t = 0; t < NT; ++t) {
            float e = expf(sm[SC + tid * NT + t] - mx);
            sm[SC + tid * NT + t] = e;
            sum += e;
        }
        float inv = 1.0f / sum;
        for (int t = 0; t < NT; ++t) sm[SC + tid * NT + t] *= inv;
    }
    __syncthreads();

    // text_vec -> CA
    {
        float sv = 0.0f;
        #pragma unroll
        for (int t = 0; t < NT; ++t)
            sv += sm[SC + lq * NT + t] * sm[FULLO + (lq * NT + t) * NH + hh];
        sm[CA + tid] = sv;
    }
    __syncthreads();

    // day LSTM: g = tv@Wih + bih + bhh; order i,f,g,o
    if (tid < NG) {
        float bsum = bih[(size_t)s * NG + tid] + bhh[(size_t)s * NG + tid];
        float d[NL];
        #pragma unroll
        for (int l = 0; l < NL; ++l) d[l] = bsum;
        for (int k = 0; k < NH; ++k) {
            float wk = Wih[((size_t)s * NH + k) * NG + tid];
            #pragma unroll
            for (int l = 0; l < NL; ++l)
                d[l] += sm[CA + l * NH + k] * wk;
        }
        #pragma unroll
        for (int l = 0; l < NL; ++l)
            sm[GATES + l * NG + tid] = d[l];
    }
    __syncthreads();
    {
        float gi = sm[GATES + lq * NG + hh];
        float gg = sm[GATES + lq * NG + 128 + hh];
        float go = sm[GATES + lq * NG + 192 + hh];
        float cd = sigf(gi) * tanhf(gg);
        sm[TQ + tid] = sigf(go) * tanhf(cd);    // hd (q is dead)
    }
    __syncthreads();

    // day attention: wave lq handles l=lq (<5)
    {
        float v = sm[B0 + lane] + sm[B1 + lane];
        for (int k4 = 0; k4 < NH; k4 += 4) {
            float4 hv = *(const float4*)&sm[TQ + lq * NH + k4];
            v += hv.x * (sm[W1OFF + (k4 + 0) * NH + lane] + sm[W2OFF + (k4 + 0) * NH + lane])
               + hv.y * (sm[W1OFF + (k4 + 1) * NH + lane] + sm[W2OFF + (k4 + 1) * NH + lane])
               + hv.z * (sm[W1OFF + (k4 + 2) * NH + lane] + sm[W2OFF + (k4 + 2) * NH + lane])
               + hv.w * (sm[W1OFF + (k4 + 3) * NH + lane] + sm[W2OFF + (k4 + 3) * NH + lane]);
        }
        v = tanhf(v) * sm[BVV + lane];
        #pragma unroll
        for (int m = 32; m > 0; m >>= 1) v += __shfl_xor(v, m, 64);
        if (lane == 0) sm[SC + lq] = v + sm[BV1];
    }
    __syncthreads();
    if (tid == 0) {
        float mx = -1e30f;
        for (int l = 0; l < NL; ++l) mx = fmaxf(mx, sm[SC + l]);
        float sum = 0.0f;
        for (int l = 0; l < NL; ++l) {
            float e = expf(sm[SC + l] - mx);
            sm[SC + l] = e;
            sum += e;
        }
        float inv = 1.0f / sum;
        for (int l = 0; l < NL; ++l) sm[SC + l] *= inv;
    }
    __syncthreads();

    if (tid < NH) {
        float fv = 0.0f;
        #pragma unroll
        for (int l = 0; l < NL; ++l)
            fv += sm[SC + l] * sm[TQ + l * NH + tid];
        fv *= lin_w[tid];
        #pragma unroll
        for (int m = 32; m > 0; m >>= 1) fv += __shfl_xor(fv, m, 64);
        if (tid == 0) {
            float val = fv + lin_b[0];
            out[s] = val > 0.0f ? val : 0.01f * val;
        }
    }
}

extern "C" void kernel_launch(void* const* d_in, const int* in_sizes, int n_in,
                              void* d_out, int out_size, void* d_ws, size_t ws_size,
                              hipStream_t stream) {
    (void)in_sizes; (void)n_in; (void)out_size; (void)ws_size;
    const float* x     = (const float*)d_in[0];
    const float* ti    = (const float*)d_in[1];
    const float* Wall  = (const float*)d_in[2];
    const float* bWall = (const float*)d_in[3];
    const float* Uall  = (const float*)d_in[4];
    const float* bUall = (const float*)d_in[5];
    const float* Wd    = (const float*)d_in[6];
    const float* bWd   = (const float*)d_in[7];
    const float* W1    = (const float*)d_in[8];
    const float* b1    = (const float*)d_in[9];
    const float* W2    = (const float*)d_in[10];
    const float* b2    = (const float*)d_in[11];
    const float* V     = (const float*)d_in[12];
    const float* bV    = (const float*)d_in[13];
    const float* Wih   = (const float*)d_in[14];
    const float* bih   = (const float*)d_in[16];
    const float* bhh   = (const float*)d_in[17];
    const float* lin_w = (const float*)d_in[18];
    const float* lin_b = (const float*)d_in[19];
    float* out = (float*)d_out;
    float* u = (float*)d_ws;   // [S][T][L][NG] = 52.4 MB

    k_gemm_u<<<NS * 2, 640, 0, stream>>>(x, Uall, bUall, u);
    k_stock<<<NS, 320, 0, stream>>>(u, ti, Wall, bWall, Wd, bWd, W1, b1, W2, b2,
                                    V, bV, Wih, bih, bhh, lin_w, lin_b, out);
}